// Round 5
// baseline (137.346 us; speedup 1.0000x reference)
//
#include <hip/hip_runtime.h>
#include <cmath>

// CapsuleLayer routing, B=64, Ni=2048, Di=16, No=32, Do=16 (fp32 in/out).
// R5: ONE fused pass over W. Per n-tile: W -> LDS (split-bf16, fragment-
// contiguous layout), MFMA uhat (D in regs), hsum = sum_d D via in-register
// reduce (routing needs only hsum - no Wd, no second W pass), 2-step routing
// softmax, c2-weighted accumulate. Partials: block-contiguous slabs (the only
// proven clean-WRITE layout), reduced + squashed by the proven k3.

#define NI 2048

typedef short bf16x8 __attribute__((ext_vector_type(8)));
typedef float f32x4 __attribute__((ext_vector_type(4)));

static __device__ __forceinline__ unsigned short f2bf(float f) {
  unsigned u = __float_as_uint(f);
  u += 0x7FFFu + ((u >> 16) & 1u);
  return (unsigned short)(u >> 16);
}
static __device__ __forceinline__ float bf2f(unsigned short h) {
  return __uint_as_float(((unsigned)h) << 16);
}

// LDS map (dwords): WA = 32 o * 64 lanes * 4dw frags (conflict-free reads)
#define WA_OFF  0      // 8192 dw
#define XB0_OFF 8192   // 512 dw: x_hi duplicated B-frags, [bt][lane]
#define XB1_OFF 8704   // 512 dw: x_lo
#define HS_OFF  9216   // 32*33 = 1056 dw: hsum[o][b]
#define C2_OFF  10272  // 32*33 = 1056 dw: c2[o][b]
#define LDS_DW  11328  // 45.3 KB

__global__ __launch_bounds__(512, 4) void caps_fused_kernel(
    const float* __restrict__ x, const float* __restrict__ W,
    float* __restrict__ partial)
{
  const int bid = blockIdx.x;
  // XCD-pair swizzle: bid and bid+8 (same XCD under %8 round-robin) share ng,
  // so the second W read hits that XCD's L2 instead of HBM.
  const int ng = ((bid >> 4) << 3) | (bid & 7);
  const int bh = (bid >> 3) & 1;
  const int t = threadIdx.x;
  const int wv = t >> 6, l = t & 63;
  const int q = l >> 4, dq = l & 15;
  const int bt = wv & 1, og = wv >> 1;   // wave: b-group (16 b) x 8 o's

  __shared__ __align__(16) float lds[LDS_DW];

  float sacc[8][4];
  #pragma unroll
  for (int oo = 0; oo < 8; ++oo)
    { sacc[oo][0]=0.f; sacc[oo][1]=0.f; sacc[oo][2]=0.f; sacc[oo][3]=0.f; }

  const int n0 = ng * 8;
  const int wd = (t >> 2) & 15, wi4 = t & 3;    // W staging decomposition
  const int xb = t >> 3, xip = t & 7;           // x staging (t<256)
  const int xbg = bh * 32 + xb;

  float4 wreg[4];
  #pragma unroll
  for (int j = 0; j < 4; ++j)
    wreg[j] = *(const float4*)(W + (size_t)n0 * 8192 + 4 * (t + 512 * j));
  float2 xreg = make_float2(0.f, 0.f);
  if (t < 256)
    xreg = *(const float2*)(x + (size_t)xbg * (NI * 16) + n0 * 16 + xip * 2);

  #pragma unroll 1
  for (int nn = 0; nn < 8; ++nn) {
    // ---- stage W: split bf16, stored per-(o,lane) fragment-contiguous ----
    {
      const int Lh = ((wi4 >> 1) << 4) + wd;   // frag-lane for hi (q 0/1)
      const int doff = (wi4 & 1) << 1;         // dword pair within frag
      #pragma unroll
      for (int j = 0; j < 4; ++j) {
        const int o = wv + (j << 3);
        unsigned short h0=f2bf(wreg[j].x), h1=f2bf(wreg[j].y),
                       h2=f2bf(wreg[j].z), h3=f2bf(wreg[j].w);
        unsigned short g0=f2bf(wreg[j].x-bf2f(h0)), g1=f2bf(wreg[j].y-bf2f(h1)),
                       g2=f2bf(wreg[j].z-bf2f(h2)), g3=f2bf(wreg[j].w-bf2f(h3));
        uint2 hi; hi.x = (unsigned)h0 | ((unsigned)h1<<16); hi.y = (unsigned)h2 | ((unsigned)h3<<16);
        uint2 lo; lo.x = (unsigned)g0 | ((unsigned)g1<<16); lo.y = (unsigned)g2 | ((unsigned)g3<<16);
        *(uint2*)&lds[WA_OFF + (o << 8) + (Lh << 2) + doff] = hi;          // q 0/1 = W_hi
        *(uint2*)&lds[WA_OFF + (o << 8) + ((Lh + 32) << 2) + doff] = lo;   // q 2/3 = W_lo
      }
    }
    // ---- stage x: split bf16 into duplicated B-frag layout ----
    if (t < 256) {
      unsigned short h0 = f2bf(xreg.x), h1 = f2bf(xreg.y);
      unsigned short g0 = f2bf(xreg.x - bf2f(h0)), g1 = f2bf(xreg.y - bf2f(h1));
      unsigned hw = (unsigned)h0 | ((unsigned)h1 << 16);
      unsigned lw = (unsigned)g0 | ((unsigned)g1 << 16);
      const int btx = xb >> 4, dqx = xb & 15;
      const int a0 = (btx << 8) + ((((xip >> 2) << 4) + dqx) << 2) + (xip & 3);
      unsigned* B0 = (unsigned*)&lds[XB0_OFF];
      unsigned* B1 = (unsigned*)&lds[XB1_OFF];
      B0[a0] = hw; B0[a0 + 128] = hw;   // duplicate into q and q+2 lane slots
      B1[a0] = lw; B1[a0 + 128] = lw;
    }
    __syncthreads();

    // ---- prefetch next n (in flight across the compute phases) ----
    if (nn < 7) {
      #pragma unroll
      for (int j = 0; j < 4; ++j)
        wreg[j] = *(const float4*)(W + (size_t)(n0 + nn + 1) * 8192 + 4 * (t + 512 * j));
      if (t < 256)
        xreg = *(const float2*)(x + (size_t)xbg * (NI * 16) + (n0 + nn + 1) * 16 + xip * 2);
    }

    // ---- MFMA uhat (D kept in regs) + hsum = sum over d rows ----
    f32x4 D[8];
    {
      bf16x8 B0f = *(const bf16x8*)&lds[XB0_OFF + (bt << 8) + (l << 2)];
      bf16x8 B1f = *(const bf16x8*)&lds[XB1_OFF + (bt << 8) + (l << 2)];
      #pragma unroll
      for (int oo = 0; oo < 8; ++oo) {
        const int o = (og << 3) + oo;
        bf16x8 A = *(const bf16x8*)&lds[WA_OFF + (o << 8) + (l << 2)];
        f32x4 d0 = {0.f, 0.f, 0.f, 0.f};
        d0 = __builtin_amdgcn_mfma_f32_16x16x32_bf16(A, B0f, d0, 0, 0, 0);
        d0 = __builtin_amdgcn_mfma_f32_16x16x32_bf16(A, B1f, d0, 0, 0, 0);
        D[oo] = d0;
        float hs = d0[0] + d0[1] + d0[2] + d0[3];   // rows q*4..q*4+3
        hs += __shfl_xor(hs, 16);
        hs += __shfl_xor(hs, 32);                    // full sum over 16 d
        if (q == 0) lds[HS_OFF + o * 33 + (bt << 4) + dq] = hs;
      }
    }
    __syncthreads();

    // ---- routing chain (proven R2 math): 256 threads, 8-lane groups ----
    if (t < 256) {
      const int bl = t >> 3, oq = t & 7;
      float h[4], b1[4], e[4];
      #pragma unroll
      for (int jj = 0; jj < 4; ++jj) h[jj] = lds[HS_OFF + (oq + (jj << 3)) * 33 + bl];
      float mx = -1e30f;
      #pragma unroll
      for (int jj = 0; jj < 4; ++jj) { b1[jj] = h[jj] * 0.03125f; mx = fmaxf(mx, b1[jj]); }
      mx = fmaxf(mx, __shfl_xor(mx, 1)); mx = fmaxf(mx, __shfl_xor(mx, 2)); mx = fmaxf(mx, __shfl_xor(mx, 4));
      float S = 0.f;
      #pragma unroll
      for (int jj = 0; jj < 4; ++jj) { e[jj] = __expf(b1[jj] - mx); S += e[jj]; }
      S += __shfl_xor(S, 1); S += __shfl_xor(S, 2); S += __shfl_xor(S, 4);
      float inv = 1.0f / S;
      float b2[4]; float mx2 = -1e30f;
      #pragma unroll
      for (int jj = 0; jj < 4; ++jj) { b2[jj] = b1[jj] + e[jj] * inv * h[jj]; mx2 = fmaxf(mx2, b2[jj]); }
      mx2 = fmaxf(mx2, __shfl_xor(mx2, 1)); mx2 = fmaxf(mx2, __shfl_xor(mx2, 2)); mx2 = fmaxf(mx2, __shfl_xor(mx2, 4));
      float S2 = 0.f;
      #pragma unroll
      for (int jj = 0; jj < 4; ++jj) { e[jj] = __expf(b2[jj] - mx2); S2 += e[jj]; }
      S2 += __shfl_xor(S2, 1); S2 += __shfl_xor(S2, 2); S2 += __shfl_xor(S2, 4);
      float inv2 = 1.0f / S2;
      #pragma unroll
      for (int jj = 0; jj < 4; ++jj) lds[C2_OFF + (oq + (jj << 3)) * 33 + bl] = e[jj] * inv2;
    }
    __syncthreads();

    // ---- c2-weighted accumulate into persistent sacc ----
    #pragma unroll
    for (int oo = 0; oo < 8; ++oo) {
      const int o = (og << 3) + oo;
      float c = lds[C2_OFF + o * 33 + (bt << 4) + dq];
      sacc[oo][0] += c * D[oo][0]; sacc[oo][1] += c * D[oo][1];
      sacc[oo][2] += c * D[oo][2]; sacc[oo][3] += c * D[oo][3];
    }
    // next staging only touches WA/XB, whose readers all passed sync2 -> safe
  }

  // ---- epilogue: block-contiguous 64 KB slab (clean-WRITE layout) ----
  const size_t slab = (size_t)((ng << 1) | bh) * 16384;
  #pragma unroll
  for (int oo = 0; oo < 8; ++oo) {
    const int o = (og << 3) + oo;
    *(float4*)(partial + slab + (size_t)((bt << 4) + dq) * 512 + o * 16 + (q << 2))
        = make_float4(sacc[oo][0], sacc[oo][1], sacc[oo][2], sacc[oo][3]);
  }
}

// ---------------- reduce 256 ng-partials + squash (proven) ----------------
__global__ __launch_bounds__(256) void caps_reduce_kernel(
    const float* __restrict__ partial, float* __restrict__ out)
{
  const int t = threadIdx.x;
  const int w4 = t >> 6, ln = t & 63;
  const int pair = blockIdx.x * 4 + w4;     // (b,o), 2048 total
  const int b = pair >> 5, o = pair & 31;
  const int d = ln & 15, cg = ln >> 4;
  const float* p = partial + (size_t)(b >> 5) * 16384
                 + (size_t)(b & 31) * 512 + o * 16 + d;
  float s = 0.f;
  #pragma unroll 8
  for (int gg = cg; gg < 256; gg += 4) s += p[(size_t)gg * 32768];
  s += __shfl_xor(s, 16); s += __shfl_xor(s, 32);    // over cg
  float s2 = s * s;
  s2 += __shfl_xor(s2, 1); s2 += __shfl_xor(s2, 2);
  s2 += __shfl_xor(s2, 4); s2 += __shfl_xor(s2, 8);  // over d
  float scale = s2 / (1.0f + s2) / sqrtf(s2 + 1e-7f);
  if (ln < 16) out[(size_t)b * 512 + o * 16 + d] = scale * s;
}

extern "C" void kernel_launch(void* const* d_in, const int* in_sizes, int n_in,
                              void* d_out, int out_size, void* d_ws, size_t ws_size,
                              hipStream_t stream) {
  const float* x = (const float*)d_in[0];   // [64,2048,16]
  const float* W = (const float*)d_in[1];   // [1,2048,32,16,16]
  if (in_sizes[0] != 64 * 2048 * 16) { const float* tmp = x; x = W; W = tmp; }
  float* out = (float*)d_out;               // [64,32,16]

  float* partial = (float*)d_ws;            // 512 slabs * 16384 f32 = 32 MB

  caps_fused_kernel<<<512, 512, 0, stream>>>(x, W, partial);
  caps_reduce_kernel<<<512, 256, 0, stream>>>(partial, out);
}